// Round 2
// baseline (1508.279 us; speedup 1.0000x reference)
//
#include <hip/hip_runtime.h>
#include <cstddef>
#include <cstdint>

// RIMCell fused pipeline for MI355X (gfx950), dtype-robust (f32 or bf16 inputs).
// A device-side detector (rim_detect) decides dtype from sw's softmax-sum
// property; every kernel that touches an ORIGINAL input branches uniformly on
// the flag. Internal intermediates are bf16 (MFMA) except the top-k-critical
// scores path (k_l, q_l) which is computed in f32 VALU at input fidelity.

typedef unsigned short u16;
typedef __bf16 bf16x8 __attribute__((ext_vector_type(8)));
typedef float f32x4 __attribute__((ext_vector_type(4)));

#define DEVFN static __device__ __forceinline__

DEVFN float ldin(const void* p, size_t i, int f) {
  return f ? (float)reinterpret_cast<const __bf16*>(p)[i]
           : reinterpret_cast<const float*>(p)[i];
}
DEVFN float bf2f(const u16* p, size_t i) {
  return (float)reinterpret_cast<const __bf16*>(p)[i];
}
DEVFN void f2bf(u16* p, size_t i, float v) {
  reinterpret_cast<__bf16*>(p)[i] = (__bf16)v;
}

// ---------------- ws layout (bytes) ----------------
constexpr size_t OFF_FLAG = 0;
constexpr size_t OFF_MASK = 256;        // 4096*6*4 = 98304
constexpr size_t OFF_WVT  = 98560;      // 400*1024*2 = 819200
constexpr size_t OFF_WQKT = 917760;     // 6*256*512*2 = 1572864
constexpr size_t OFF_WVT_ = 2490624;    // 6*2048*512*2 = 12582912
constexpr size_t OFF_WOT  = 15073536;   // 6*512*2048*2 = 12582912
constexpr size_t OFF_WXCT = 27656448;   // 6*1536*400*2 = 7372800
constexpr size_t OFF_WHCT = 35029248;   // 6*1536*512*2 = 9437184
constexpr size_t OFF_HY   = 44466432;   // 4096*3072*2 = 25165824
constexpr size_t ARENA    = 69632256;
constexpr size_t A_INP    = ARENA;      // inputs bf16 4096*2400*2 = 19660800
constexpr size_t A_P1     = 89293056;   // overlayable after rim_scores
constexpr size_t A_KL     = 89293056;   // k_l0 f32 4096*64*4 = 1048576
constexpr size_t A_QL     = 90341632;   // q_l f32 4096*384*4 = 6291456
constexpr size_t A_VL     = 96633088;   // v_l0 bf16 4096*400*2 = 3276800
// P2 chunk: Ggx at A_P1, Ggh at A_P1 + R2*18432 (needs A_P1 + R2*36864)
// P3 chunk: qk at A_INP, v at +R3*3072, ctx at +R3*3072+R3*24576 (A_INP + R3*52224)

// ---------------- dtype detection ----------------
__global__ void rim_detect(const void* sw, int* flagp) {
  if (threadIdx.x == 0) {
    float s = 0.f;
    for (int i = 0; i < 24; i++)
      s += (float)reinterpret_cast<const __bf16*>(sw)[i];
    // bf16 data: sum of 6 softmax rows ~= 6.  f32 data read as bf16: garbage.
    flagp[0] = (s > 5.5f && s < 6.5f) ? 1 : 0;
  }
}

// ---------------- GEMM: C = A @ Bt^T, 128x128 tile, mfma 16x16x32 bf16 -------
// ADT: 0 = A is ws bf16, 1 = A is original input (dual dtype).
// EPI: 2 = bf16 + bias(orig input), 3 = bf16, 4 = final (mask-select, dual out)
template<int ADT>
DEVFN bf16x8 ldA(const void* A, size_t idx, int f) {
  if constexpr (ADT == 0) {
    return *reinterpret_cast<const bf16x8*>(reinterpret_cast<const __bf16*>(A) + idx);
  } else {
    if (f)
      return *reinterpret_cast<const bf16x8*>(reinterpret_cast<const __bf16*>(A) + idx);
    const f32x4* fp = reinterpret_cast<const f32x4*>(reinterpret_cast<const float*>(A) + idx);
    f32x4 lo = fp[0], hi = fp[1];
    bf16x8 r;
#pragma unroll
    for (int q = 0; q < 4; q++) { r[q] = (__bf16)lo[q]; r[q + 4] = (__bf16)hi[q]; }
    return r;
  }
}

template<int EPI, int ADT>
__global__ __launch_bounds__(256)
void rim_gemm(const void* __restrict__ A_, long A0, long lda, long Az,
              const u16* __restrict__ B_, long Bz,
              void* __restrict__ C_, long C0, long ldc, long Cz,
              int M, int N, int K,
              const void* __restrict__ bias,
              const u16* __restrict__ hyp,
              const float* __restrict__ maskp,
              const void* __restrict__ hsp,
              const int* __restrict__ flagp)
{
  __shared__ __align__(16) __bf16 As[128 * 32];
  __shared__ __align__(16) __bf16 Bs[128 * 32];
  const int f = flagp[0];
  const int t = threadIdx.x;
  const int m0 = blockIdx.x * 128, n0 = blockIdx.y * 128, z = blockIdx.z;
  const __bf16* Bb = reinterpret_cast<const __bf16*>(B_) + (size_t)z * Bz;
  const int lane = t & 63, w = t >> 6;
  const int wm = (w & 1) * 64, wn = (w >> 1) * 64;
  const int lr = lane & 15, lk = (lane >> 4) * 8;

  f32x4 acc[4][4];
#pragma unroll
  for (int i = 0; i < 4; i++)
#pragma unroll
    for (int j = 0; j < 4; j++)
#pragma unroll
      for (int r = 0; r < 4; r++) acc[i][j][r] = 0.f;

  const int r0 = t >> 2;
  const int kc0 = (t & 3) << 3;

  for (int k0 = 0; k0 < K; k0 += 32) {
#pragma unroll
    for (int it = 0; it < 2; it++) {
      int row = r0 + it * 64;
      int gk = k0 + kc0;
      bf16x8 av, bv8;
#pragma unroll
      for (int q = 0; q < 8; q++) { av[q] = (__bf16)0.f; bv8[q] = (__bf16)0.f; }
      int gm = m0 + row;
      if (gm < M && gk < K)
        av = ldA<ADT>(A_, (size_t)A0 + (size_t)z * Az + (size_t)gm * lda + gk, f);
      int gn = n0 + row;
      if (gn < N && gk < K)
        bv8 = *reinterpret_cast<const bf16x8*>(Bb + (size_t)gn * (size_t)K + gk);
      *reinterpret_cast<bf16x8*>(&As[row * 32 + kc0]) = av;
      *reinterpret_cast<bf16x8*>(&Bs[row * 32 + kc0]) = bv8;
    }
    __syncthreads();
    bf16x8 af[4], bg[4];
#pragma unroll
    for (int i = 0; i < 4; i++)
      af[i] = *reinterpret_cast<const bf16x8*>(&As[(wm + i * 16 + lr) * 32 + lk]);
#pragma unroll
    for (int j = 0; j < 4; j++)
      bg[j] = *reinterpret_cast<const bf16x8*>(&Bs[(wn + j * 16 + lr) * 32 + lk]);
#pragma unroll
    for (int i = 0; i < 4; i++)
#pragma unroll
      for (int j = 0; j < 4; j++)
        acc[i][j] = __builtin_amdgcn_mfma_f32_16x16x32_bf16(af[i], bg[j], acc[i][j], 0, 0, 0);
    __syncthreads();
  }

  const int rq = (lane >> 4) * 4;  // C/D: row=(lane>>4)*4+reg, col=lane&15
  const int cq = lane & 15;
#pragma unroll
  for (int i = 0; i < 4; i++) {
#pragma unroll
    for (int j = 0; j < 4; j++) {
      int cg = n0 + wn + j * 16 + cq;
      if (cg >= N) continue;
#pragma unroll
      for (int r = 0; r < 4; r++) {
        int rg = m0 + wm + i * 16 + rq + r;
        if (rg >= M) continue;
        float v = acc[i][j][r];
        size_t cidx = (size_t)rg * ldc + (size_t)z * Cz + cg;
        if constexpr (EPI == 2) {
          f2bf((u16*)C_, C0 + cidx, v + ldin(bias, cg, f));
        } else if constexpr (EPI == 3) {
          f2bf((u16*)C_, C0 + cidx, v);
        } else {
          float mk = maskp[(size_t)rg * 6 + z];
          if (mk > 0.5f) {
            float o = v + bf2f(hyp, cidx);
            if (f) f2bf((u16*)C_, C0 + cidx, o);
            else   reinterpret_cast<float*>(C_)[C0 + cidx] = o;
          } else {
            if (f) reinterpret_cast<u16*>(C_)[C0 + cidx] =
                       reinterpret_cast<const u16*>(hsp)[C0 + cidx];
            else   reinterpret_cast<float*>(C_)[C0 + cidx] =
                       reinterpret_cast<const float*>(hsp)[C0 + cidx];
          }
        }
      }
    }
  }
}

// ---------------- transpose to bf16: out[z][n][k] = in[z][k][n] ----------------
__global__ void rim_transpose(const void* __restrict__ in, u16* __restrict__ out,
                              int N, int K, long in_z, long out_z, long total,
                              const int* __restrict__ flagp)
{
  const int f = flagp[0];
  long idx = (long)blockIdx.x * 256 + threadIdx.x;
  if (idx >= total) return;
  long k = idx % K;
  long t2 = idx / K;
  long n = t2 % N;
  long z = t2 / N;
  f2bf(out, z * out_z + n * (long)K + k, ldin(in, z * in_z + k * (long)N + n, f));
}

// ------- combined GRU weight, transposed: out[u][o][i] = sum_s sw[u,s]*gw[s][i][o]
__global__ void rim_gruw(const void* __restrict__ sw, const void* __restrict__ gw,
                         u16* __restrict__ out, int IVH, long total,
                         const int* __restrict__ flagp)
{
  const int f = flagp[0];
  long idx = (long)blockIdx.x * 256 + threadIdx.x;
  if (idx >= total) return;
  long i = idx % IVH;
  long t2 = idx / IVH;
  long o = t2 % 1536;
  long u = t2 / 1536;
  float acc = 0.f;
#pragma unroll
  for (int s = 0; s < 4; s++)
    acc += ldin(sw, u * 4 + s, f) * ldin(gw, ((size_t)s * IVH + i) * 1536 + o, f);
  f2bf(out, idx, acc);
}

// ---------------- k_l0 = x @ Wk + bk, full input fidelity (f32 VALU) ----------
__global__ __launch_bounds__(256)
void rim_kl(const void* __restrict__ x, const void* __restrict__ Wk,
            const void* __restrict__ bk, float* __restrict__ k_l0,
            const int* __restrict__ flagp)
{
  const int f = flagp[0];
  __shared__ float xs[4096];
  __shared__ float red[16 * 64];
  int b0 = blockIdx.x * 4, t = threadIdx.x;
  for (int i = t; i < 4096; i += 256) xs[i] = ldin(x, (size_t)b0 * 1024 + i, f);
  __syncthreads();
  int d = t & 63, kq = t >> 6;
  float acc[4] = {0.f, 0.f, 0.f, 0.f};
  for (int k = kq * 256; k < kq * 256 + 256; k++) {
    float w = ldin(Wk, (size_t)k * 64 + d, f);
#pragma unroll
    for (int bb = 0; bb < 4; bb++) acc[bb] += xs[bb * 1024 + k] * w;
  }
#pragma unroll
  for (int bb = 0; bb < 4; bb++) red[(kq * 4 + bb) * 64 + d] = acc[bb];
  __syncthreads();
  if (t < 64) {
    for (int bb = 0; bb < 4; bb++) {
      float s = ldin(bk, t, f);
#pragma unroll
      for (int kq2 = 0; kq2 < 4; kq2++) s += red[(kq2 * 4 + bb) * 64 + t];
      k_l0[(size_t)(b0 + bb) * 64 + t] = s;
    }
  }
}

// ---------------- q_l[b][u][d] = sum_h hs[b,u,h]*Wq[u,h,d] (f32 VALU) ---------
__global__ __launch_bounds__(256)
void rim_ql(const void* __restrict__ hs, const void* __restrict__ Wq,
            float* __restrict__ q_l, const int* __restrict__ flagp)
{
  const int f = flagp[0];
  __shared__ float hss[12288];
  int b0 = blockIdx.x * 4, t = threadIdx.x;
  for (int i = t; i < 12288; i += 256) hss[i] = ldin(hs, (size_t)b0 * 3072 + i, f);
  __syncthreads();
  for (int o = t; o < 384; o += 256) {
    int u = o >> 6, d = o & 63;
    float a0 = 0.f, a1 = 0.f, a2 = 0.f, a3 = 0.f;
    const int hb = u * 512;
    for (int h = 0; h < 512; h++) {
      float w = ldin(Wq, ((size_t)hb + h) * 64 + d, f);
      a0 += hss[hb + h] * w;
      a1 += hss[3072 + hb + h] * w;
      a2 += hss[6144 + hb + h] * w;
      a3 += hss[9216 + hb + h] * w;
    }
    q_l[(size_t)(b0 + 0) * 384 + o] = a0;
    q_l[(size_t)(b0 + 1) * 384 + o] = a1;
    q_l[(size_t)(b0 + 2) * 384 + o] = a2;
    q_l[(size_t)(b0 + 3) * 384 + o] = a3;
  }
}

// ---------------- scores / top-4 mask / 2-way softmax / inputs ----------------
__global__ __launch_bounds__(256)
void rim_scores(const float* __restrict__ q_l, const float* __restrict__ k_l0,
                const void* __restrict__ bk, const u16* __restrict__ v_l0,
                const void* __restrict__ bv, float* __restrict__ maskf,
                u16* __restrict__ inputs, const int* __restrict__ flagp)
{
  const int f = flagp[0];
  int b = blockIdx.x;
  int t = threadIdx.x;
  int lane = t & 63;
  __shared__ float s0[6], s1[6], sm[6], sp[6];
  if (t < 64) {
    float kv = k_l0[(size_t)b * 64 + lane];
    for (int u = 0; u < 6; u++) {
      float p = q_l[((size_t)b * 6 + u) * 64 + lane] * kv;
      for (int off = 32; off; off >>= 1) p += __shfl_down(p, off);
      if (lane == 0) s0[u] = p * 0.125f;
    }
  } else if (t < 128) {
    float kv = ldin(bk, lane, f);
    for (int u = 0; u < 6; u++) {
      float p = q_l[((size_t)b * 6 + u) * 64 + lane] * kv;
      for (int off = 32; off; off >>= 1) p += __shfl_down(p, off);
      if (lane == 0) s1[u] = p * 0.125f;
    }
  }
  __syncthreads();
  if (t == 0) {
    for (int u = 0; u < 6; u++) {
      int cnt = 0;
      for (int u2 = 0; u2 < 6; u2++)
        if (s0[u2] > s0[u] || (s0[u2] == s0[u] && u2 < u)) cnt++;
      float mk = (cnt < 4) ? 1.0f : 0.0f;  // jax top_k tie-break: lower index wins
      sm[u] = mk;
      maskf[(size_t)b * 6 + u] = mk;
      sp[u] = 1.0f / (1.0f + expf(s1[u] - s0[u]));  // p(t=0) of 2-way softmax
    }
  }
  __syncthreads();
  for (int idx = t; idx < 2400; idx += 256) {
    int u = idx / 400, j = idx % 400;
    float val = sm[u] * (sp[u] * bf2f(v_l0, (size_t)b * 400 + j) +
                         (1.0f - sp[u]) * ldin(bv, j, f));
    f2bf(inputs, ((size_t)b * 6 + u) * 400 + j, val);
  }
}

// ---------------- GRU elementwise ----------------
__global__ void rim_gru(const u16* __restrict__ Ggx, const u16* __restrict__ Ggh,
                        const void* __restrict__ hs, long R0,
                        u16* __restrict__ hy, long total,
                        const int* __restrict__ flagp)
{
  const int f = flagp[0];
  long idx = (long)blockIdx.x * 256 + threadIdx.x;
  if (idx >= total) return;
  long bu = idx >> 9;
  int h = idx & 511;
  size_t gb = (size_t)bu * 1536 + h;
  float xr = bf2f(Ggx, gb), xz = bf2f(Ggx, gb + 512), xn = bf2f(Ggx, gb + 1024);
  float hr = bf2f(Ggh, gb), hz = bf2f(Ggh, gb + 512), hn = bf2f(Ggh, gb + 1024);
  float r = 1.f / (1.f + expf(-(xr + hr)));
  float zz = 1.f / (1.f + expf(-(xz + hz)));
  float n = tanhf(xn + r * hn);
  float hv = ldin(hs, R0 + idx, f);
  f2bf(hy, idx, n + zz * (hv - n));
}

// ---------------- per-b attention: att -> softmax*mask -> ctx ----------------
__global__ __launch_bounds__(256)
void rim_attn(const u16* __restrict__ qk, const float* __restrict__ maskp,
              const u16* __restrict__ v, u16* __restrict__ ctx)
{
  int bl = blockIdx.x;
  int t = threadIdx.x;
  __shared__ float qs[1536];
  __shared__ float aps[144];
  __shared__ __align__(16) u16 vs[12288];
  for (int idx = t; idx < 1536; idx += 256)
    qs[idx] = bf2f(qk, (size_t)bl * 1536 + idx);
  for (int idx = t; idx < 1536; idx += 256)
    *reinterpret_cast<bf16x8*>(&vs[idx * 8]) =
        *reinterpret_cast<const bf16x8*>(
            reinterpret_cast<const __bf16*>(v) + (size_t)bl * 12288 + idx * 8);
  __syncthreads();
  if (t < 144) {
    int h = t / 36, r6 = t % 36, uq = r6 / 6, uk = r6 % 6;
    float s = 0.f;
#pragma unroll
    for (int d = 0; d < 32; d++)
      s += qs[uq * 256 + h * 32 + d] * qs[uk * 256 + 128 + h * 32 + d];
    aps[t] = s * 0.17677669529663687f;  // 1/sqrt(32)
  }
  __syncthreads();
  if (t < 24) {
    int h = t / 6, uq = t % 6;
    float* row = &aps[h * 36 + uq * 6];
    float mx = row[0];
    for (int k = 1; k < 6; k++) mx = fmaxf(mx, row[k]);
    float e[6], sum = 0.f;
    for (int k = 0; k < 6; k++) { e[k] = expf(row[k] - mx); sum += e[k]; }
    float mk = maskp[(size_t)bl * 6 + uq] / sum;
    for (int k = 0; k < 6; k++) row[k] = e[k] * mk;
  }
  __syncthreads();
  for (int idx = t; idx < 12288; idx += 256) {
    int uq = idx >> 11, g = idx & 2047, h = g >> 9;
    const float* ar = &aps[h * 36 + uq * 6];
    float acc = 0.f;
#pragma unroll
    for (int k = 0; k < 6; k++) acc += ar[k] * bf2f(vs, k * 2048 + g);
    f2bf(ctx, ((size_t)bl * 6 + uq) * 2048 + g, acc);
  }
}

// ---------------- host ----------------
extern "C" void kernel_launch(void* const* d_in, const int* in_sizes, int n_in,
                              void* d_out, int out_size, void* d_ws, size_t ws_size,
                              hipStream_t stream)
{
  (void)in_sizes; (void)n_in; (void)out_size;
  const void* x   = d_in[0];
  const void* hs  = d_in[1];
  const void* Wk  = d_in[2];
  const void* bk  = d_in[3];
  const void* Wv  = d_in[4];
  const void* bv  = d_in[5];
  const void* Wq  = d_in[6];
  const void* Wq_ = d_in[7];
  const void* Wk_ = d_in[8];
  const void* Wv_ = d_in[9];
  const void* Wo_ = d_in[10];
  const void* sw  = d_in[11];
  const void* gwx = d_in[12];
  const void* gwh = d_in[13];
  char* ws = (char*)d_ws;

  int*   flagp = (int*)(ws + OFF_FLAG);
  float* maskf = (float*)(ws + OFF_MASK);
  u16* WvT   = (u16*)(ws + OFF_WVT);
  u16* WqkT  = (u16*)(ws + OFF_WQKT);
  u16* WvT_  = (u16*)(ws + OFF_WVT_);
  u16* WoT   = (u16*)(ws + OFF_WOT);
  u16* WxcT  = (u16*)(ws + OFF_WXCT);
  u16* WhcT  = (u16*)(ws + OFF_WHCT);
  u16* hy    = (u16*)(ws + OFF_HY);
  u16* inputs = (u16*)(ws + A_INP);
  float* k_l0 = (float*)(ws + A_KL);
  float* q_l  = (float*)(ws + A_QL);
  u16* v_l0   = (u16*)(ws + A_VL);

  // adaptive chunk sizes (ws_size is constant per session -> graph-consistent)
  int R2 = 256, R3 = 256;
  {
    const int cand[5] = {4096, 2048, 1024, 512, 256};
    for (int i = 0; i < 5; i++)
      if (A_P1 + (size_t)cand[i] * 36864 <= ws_size) { R2 = cand[i]; break; }
    for (int i = 0; i < 5; i++)
      if (ARENA + (size_t)cand[i] * 52224 <= ws_size) { R3 = cand[i]; break; }
  }

  rim_detect<<<dim3(1), dim3(64), 0, stream>>>(sw, flagp);

  auto T = [&](const void* in, u16* outp, int N, int K, long iz, long oz, int Z) {
    long total = (long)Z * N * K;
    rim_transpose<<<dim3((unsigned)((total + 255) / 256)), dim3(256), 0, stream>>>(
        in, outp, N, K, iz, oz, total, flagp);
  };
  T(Wv, WvT, 400, 1024, 0, 0, 1);
  T(Wq_, WqkT, 128, 512, 65536, 131072, 6);
  T(Wk_, WqkT + 65536, 128, 512, 65536, 131072, 6);
  T(Wv_, WvT_, 2048, 512, 1048576, 1048576, 6);
  T(Wo_, WoT, 512, 2048, 1048576, 1048576, 6);
  {
    long tx = 6L * 1536 * 400, th = 6L * 1536 * 512;
    rim_gruw<<<dim3((unsigned)((tx + 255) / 256)), dim3(256), 0, stream>>>(sw, gwx, WxcT, 400, tx, flagp);
    rim_gruw<<<dim3((unsigned)((th + 255) / 256)), dim3(256), 0, stream>>>(sw, gwh, WhcT, 512, th, flagp);
  }

  auto G = [&](int epi, int adt, const void* A, long A0, long lda, long Az,
               const u16* B, long Bz, void* C, long C0, long ldc, long Cz,
               int M, int N, int K, int Z,
               const void* bias, const u16* hyp, const float* mp, const void* hsp) {
    dim3 g((M + 127) / 128, (N + 127) / 128, Z), blk(256);
    if (epi == 2 && adt == 1)
      rim_gemm<2, 1><<<g, blk, 0, stream>>>(A, A0, lda, Az, B, Bz, C, C0, ldc, Cz, M, N, K, bias, hyp, mp, hsp, flagp);
    else if (epi == 3 && adt == 1)
      rim_gemm<3, 1><<<g, blk, 0, stream>>>(A, A0, lda, Az, B, Bz, C, C0, ldc, Cz, M, N, K, bias, hyp, mp, hsp, flagp);
    else if (epi == 3 && adt == 0)
      rim_gemm<3, 0><<<g, blk, 0, stream>>>(A, A0, lda, Az, B, Bz, C, C0, ldc, Cz, M, N, K, bias, hyp, mp, hsp, flagp);
    else
      rim_gemm<4, 0><<<g, blk, 0, stream>>>(A, A0, lda, Az, B, Bz, C, C0, ldc, Cz, M, N, K, bias, hyp, mp, hsp, flagp);
  };

  // scores path: full-fidelity f32 for k_l0/q_l (top-k safety); v_l0 bf16 MFMA
  rim_kl<<<dim3(1024), dim3(256), 0, stream>>>(x, Wk, bk, k_l0, flagp);
  rim_ql<<<dim3(1024), dim3(256), 0, stream>>>(hs, Wq, q_l, flagp);
  G(2, 1, x, 0, 1024, 0, WvT, 0, v_l0, 0, 400, 0, 4096, 400, 1024, 1,
    bv, nullptr, nullptr, nullptr);
  rim_scores<<<dim3(4096), dim3(256), 0, stream>>>(q_l, k_l0, bk, v_l0, bv,
                                                   maskf, inputs, flagp);

  // GRU in chunks of R2 rows
  u16* Ggx = (u16*)(ws + A_P1);
  u16* Ggh = (u16*)(ws + A_P1 + (size_t)R2 * 18432);
  for (int r0 = 0; r0 < 4096; r0 += R2) {
    G(3, 1, hs, (long)r0 * 3072, 3072, 512, WhcT, 786432, Ggh, 0, 9216, 1536,
      R2, 1536, 512, 6, nullptr, nullptr, nullptr, nullptr);
    G(3, 0, inputs, (long)r0 * 2400, 2400, 400, WxcT, 614400, Ggx, 0, 9216, 1536,
      R2, 1536, 400, 6, nullptr, nullptr, nullptr, nullptr);
    long total = (long)R2 * 3072;
    rim_gru<<<dim3((unsigned)(total / 256)), dim3(256), 0, stream>>>(
        Ggx, Ggh, hs, (long)r0 * 3072, hy + (size_t)r0 * 3072, total, flagp);
  }

  // attention + output in chunks of R3 rows
  u16* qk_c  = (u16*)(ws + A_INP);
  u16* v_c   = (u16*)(ws + A_INP + (size_t)R3 * 3072);
  u16* ctx_c = (u16*)(ws + A_INP + (size_t)R3 * 3072 + (size_t)R3 * 24576);
  for (int r0 = 0; r0 < 4096; r0 += R3) {
    G(3, 0, hy, (long)r0 * 3072, 3072, 512, WqkT, 131072, qk_c, 0, 1536, 256,
      R3, 256, 512, 6, nullptr, nullptr, nullptr, nullptr);
    G(3, 0, hy, (long)r0 * 3072, 3072, 512, WvT_, 1048576, v_c, 0, 12288, 2048,
      R3, 2048, 512, 6, nullptr, nullptr, nullptr, nullptr);
    rim_attn<<<dim3(R3), dim3(256), 0, stream>>>(qk_c, maskf + (size_t)r0 * 6, v_c, ctx_c);
    G(4, 0, ctx_c, 0, 12288, 2048, WoT, 1048576, d_out, (long)r0 * 3072, 3072, 512,
      R3, 512, 2048, 6, nullptr, hy + (size_t)r0 * 3072, maskf + (size_t)r0 * 6, hs);
  }
}